// Round 6
// baseline (106.904 us; speedup 1.0000x reference)
//
#include <hip/hip_runtime.h>
#include <hip/hip_cooperative_groups.h>
#include <math.h>

namespace cg = cooperative_groups;

#define B_ 2
#define S_ 2048
#define M_ 1024
#define R_ 64
#define N_ 16
#define NC 64          // s-chunks
#define CH (S_/NC)     // 32

// ws float offsets (shared by mega + fallback paths)
#define DT_OFF  0                    // 4,194,304 (fallback only)
#define P_OFF   4194304              // 2,097,152
#define H_OFF   6291456              // 2,097,152
#define BWT_OFF 8388608              // 16,384 (fallback only)
#define CWT_OFF 8404992              // 16,384 (fallback only)
#define PB_OFF  8421376              // 131,072
#define PC_OFF  8552448              // 131,072

// ============================================================================
// MEGA: everything in one cooperative kernel.
// grid 2048 x 256, 8 blocks/CU exactly (20 KiB LDS, <=64 VGPR).
// LDS map (floats): [0..2047]=dt tile  [2048..4095]=u tile (aliases: phaseB u
// scratch rows / delta staging)  [4096..4607]=B tile  [4608..5119]=C tile
// (alias: phaseB reduction buffer).
// ============================================================================
__global__ __launch_bounds__(256, 8) void k_mega(
    const float* __restrict__ u, const float* __restrict__ delta,
    const float* __restrict__ Wdt, const float* __restrict__ bdt,
    const float* __restrict__ A_log, const float* __restrict__ Dskip,
    const float* __restrict__ Bw, const float* __restrict__ Cw,
    float* __restrict__ P, float* __restrict__ H,
    float* __restrict__ Bp, float* __restrict__ Cp,
    float* __restrict__ out)
{
    cg::grid_group grid = cg::this_grid();
    __shared__ float lds[5120];
    const int tid = threadIdx.x;
    const int bid = blockIdx.x;
    const int b   = bid >> 10;
    const int c   = (bid >> 4) & 63;
    const int m0  = (bid & 15) << 6;
    const int s0  = c << 5;

    // ---------- Phase B: B/C projections (blocks 0..511, 8 rows each) ----------
    if (bid < 512) {
        const int msp = tid >> 4;          // 0..15 : 64-wide m-slice
        const int nn  = tid & 15;
        const float4* wB4 = reinterpret_cast<const float4*>(Bw + (size_t)nn * M_ + msp * 64);
        const float4* wC4 = reinterpret_cast<const float4*>(Cw + (size_t)nn * M_ + msp * 64);
        for (int half = 0; half < 2; ++half) {
            const int rowBase = bid * 8 + half * 4;        // flat bs rows
            for (int i = tid; i < 1024; i += 256) {        // 4 rows x 256 float4
                int r = i >> 8, kq = i & 255;
                *reinterpret_cast<float4*>(&lds[r * 1024 + kq * 4]) =
                    *reinterpret_cast<const float4*>(&u[(size_t)(rowBase + r) * M_ + kq * 4]);
            }
            __syncthreads();
            float accB[4] = {0.f,0.f,0.f,0.f}, accC[4] = {0.f,0.f,0.f,0.f};
#pragma unroll 1
            for (int k4 = 0; k4 < 16; ++k4) {
                float4 wb = wB4[k4], wc = wC4[k4];
#pragma unroll
                for (int r = 0; r < 4; ++r) {
                    float4 uv = *reinterpret_cast<const float4*>(&lds[r * 1024 + msp * 64 + k4 * 4]);
                    accB[r] = fmaf(uv.x, wb.x, accB[r]);
                    accB[r] = fmaf(uv.y, wb.y, accB[r]);
                    accB[r] = fmaf(uv.z, wb.z, accB[r]);
                    accB[r] = fmaf(uv.w, wb.w, accB[r]);
                    accC[r] = fmaf(uv.x, wc.x, accC[r]);
                    accC[r] = fmaf(uv.y, wc.y, accC[r]);
                    accC[r] = fmaf(uv.z, wc.z, accC[r]);
                    accC[r] = fmaf(uv.w, wc.w, accC[r]);
                }
            }
            // reduce msp within wave (4 groups) via butterfly, then cross-wave
#pragma unroll
            for (int r = 0; r < 4; ++r) {
                accB[r] += __shfl_xor(accB[r], 16, 64);
                accB[r] += __shfl_xor(accB[r], 32, 64);
                accC[r] += __shfl_xor(accC[r], 16, 64);
                accC[r] += __shfl_xor(accC[r], 32, 64);
            }
            __syncthreads();                                // uScr reads done
            {
                const int w  = tid >> 6;
                const int ln = tid & 63;
                if (ln < 16) {                              // ln == nn here
#pragma unroll
                    for (int r = 0; r < 4; ++r) {
                        lds[4096 + (w * 4 + r) * 16 + ln]       = accB[r];
                        lds[4096 + 256 + (w * 4 + r) * 16 + ln] = accC[r];
                    }
                }
            }
            __syncthreads();
            if (tid < 64) {
                int r = tid >> 4, n2 = tid & 15;
                float sB = 0.f, sC = 0.f;
#pragma unroll
                for (int w2 = 0; w2 < 4; ++w2) {
                    sB += lds[4096 + (w2 * 4 + r) * 16 + n2];
                    sC += lds[4096 + 256 + (w2 * 4 + r) * 16 + n2];
                }
                Bp[(size_t)(rowBase + r) * N_ + n2] = sB;
                Cp[(size_t)(rowBase + r) * N_ + n2] = sC;
            }
            __syncthreads();
        }
    }

    // ---------- Phase A: dt for this block's tile -> lds[0..2047] ----------
    for (int i = tid; i < 512; i += 256) {                  // delta: 32 x 64
        int s = i >> 4, kq = (i & 15) * 4;
        *reinterpret_cast<float4*>(&lds[2048 + s * 64 + kq]) =
            *reinterpret_cast<const float4*>(&delta[(size_t)(b * S_ + s0 + s) * R_ + kq]);
    }
    __syncthreads();
    {
        const int mlA = tid & 63;
        const int sg  = tid >> 6;                           // 8 s-rows each
        const int mA  = m0 + mlA;
        float bias = bdt[mA];
        float acc[8];
#pragma unroll
        for (int i = 0; i < 8; ++i) acc[i] = bias;
        const float4* W4 = reinterpret_cast<const float4*>(Wdt + (size_t)mA * R_);
#pragma unroll 1
        for (int kb = 0; kb < 8; ++kb) {
            float4 w0 = W4[kb * 2], w1 = W4[kb * 2 + 1];
#pragma unroll
            for (int i = 0; i < 8; ++i) {
                const float* dr = &lds[2048 + (sg * 8 + i) * 64 + kb * 8];
                float4 d0 = *reinterpret_cast<const float4*>(dr);
                float4 d1 = *reinterpret_cast<const float4*>(dr + 4);
                acc[i] = fmaf(d0.x, w0.x, acc[i]);
                acc[i] = fmaf(d0.y, w0.y, acc[i]);
                acc[i] = fmaf(d0.z, w0.z, acc[i]);
                acc[i] = fmaf(d0.w, w0.w, acc[i]);
                acc[i] = fmaf(d1.x, w1.x, acc[i]);
                acc[i] = fmaf(d1.y, w1.y, acc[i]);
                acc[i] = fmaf(d1.z, w1.z, acc[i]);
                acc[i] = fmaf(d1.w, w1.w, acc[i]);
            }
        }
#pragma unroll
        for (int i = 0; i < 8; ++i) {                       // softplus + clip
            float a2 = acc[i];
            float sp = fmaxf(a2, 0.f) + log1pf(expf(-fabsf(a2)));
            sp = fminf(fmaxf(sp, 1e-6f), 10.0f);
            lds[(sg * 8 + i) * 64 + mlA] = sp;              // disjoint from delta region
        }
    }
    __syncthreads();                                        // delta reads + dt writes done
    for (int i = tid; i < 512; i += 256) {                  // u tile overwrites delta region
        int s = i >> 4, mq = (i & 15) * 4;
        *reinterpret_cast<float4*>(&lds[2048 + s * 64 + mq]) =
            *reinterpret_cast<const float4*>(&u[((size_t)(b * S_ + s0 + s)) * M_ + m0 + mq]);
    }

    const int lane = tid & 63;
    const int wv   = tid >> 6;
    const int ml   = wv * 16 + (lane & 15);
    const int m    = m0 + ml;
    const int ng   = lane >> 4;
    const int n0   = ng * 4;
    float Aa[4];
#pragma unroll
    for (int j = 0; j < 4; ++j) {
        float a2 = -expf(A_log[(size_t)(n0 + j) * M_ + m]);
        Aa[j] = fminf(fmaxf(a2, -10.f), -1e-6f);
    }
    const float Dm = Dskip[m];

    grid.sync();    // Bp/Cp ready everywhere; also block-barrier for u staging

    // stage B/C tiles
    {
        const size_t baseBC = (size_t)(b * S_ + s0) * N_;
        if (tid < 128) {
            *reinterpret_cast<float4*>(&lds[4096 + tid * 4]) =
                *reinterpret_cast<const float4*>(&Bp[baseBC + tid * 4]);
        } else {
            *reinterpret_cast<float4*>(&lds[4608 + (tid - 128) * 4]) =
                *reinterpret_cast<const float4*>(&Cp[baseBC + (tid - 128) * 4]);
        }
    }
    __syncthreads();

    // ---------- pass1: chunk-local (g = prod e^a, h) ----------
    float h[4] = {0.f,0.f,0.f,0.f}, g[4] = {1.f,1.f,1.f,1.f};
    for (int s = 0; s < CH; ++s) {
        float dtv = lds[s * 64 + ml];
        float uv  = lds[2048 + s * 64 + ml];
        float du  = dtv * uv;
        float4 bv = *reinterpret_cast<const float4*>(&lds[4096 + s * 16 + n0]);
        float bb[4] = {bv.x, bv.y, bv.z, bv.w};
#pragma unroll
        for (int j = 0; j < 4; ++j) {
            float ea = __expf(dtv * Aa[j]);
            h[j] = fmaf(ea, h[j], g[j] * (du * bb[j]));
            g[j] *= ea;
        }
    }
#pragma unroll
    for (int j = 0; j < 4; ++j) {
        size_t o = ((size_t)((b * N_ + n0 + j) * NC + c)) * M_ + m;
        P[o] = g[j];
        H[o] = h[j];
    }

    grid.sync();

    // ---------- pass2: exclusive chunk prefix (blocks 0..127) ----------
    if (bid < 128) {
        const int idx = bid * 256 + tid;                    // 0..32767
        const int mm  = idx & (M_ - 1);
        const int nn2 = (idx >> 10) & 15;
        const int bb2 = idx >> 14;
        const size_t base2 = ((size_t)(bb2 * N_ + nn2) * NC) * M_ + mm;
        float grun = 1.f, hrun = 0.f;
#pragma unroll 1
        for (int c0 = 0; c0 < NC; c0 += 8) {
            float pv[8], hv[8];
#pragma unroll
            for (int t = 0; t < 8; ++t) {
                pv[t] = P[base2 + (size_t)(c0 + t) * M_];
                hv[t] = H[base2 + (size_t)(c0 + t) * M_];
            }
#pragma unroll
            for (int t = 0; t < 8; ++t) {
                P[base2 + (size_t)(c0 + t) * M_] = grun;
                H[base2 + (size_t)(c0 + t) * M_] = hrun;
                hrun = fmaf(pv[t], hrun, grun * hv[t]);
                grun *= pv[t];
            }
        }
    }

    grid.sync();

    // ---------- pass3: full recurrence + y + out (LDS tiles still resident) ----------
#pragma unroll
    for (int j = 0; j < 4; ++j) {
        size_t o = ((size_t)((b * N_ + n0 + j) * NC + c)) * M_ + m;
        g[j] = P[o];
        h[j] = H[o];
    }
    for (int s = 0; s < CH; ++s) {
        float dtv = lds[s * 64 + ml];
        float uv  = lds[2048 + s * 64 + ml];
        float du  = dtv * uv;
        float4 bv = *reinterpret_cast<const float4*>(&lds[4096 + s * 16 + n0]);
        float4 cv = *reinterpret_cast<const float4*>(&lds[4608 + s * 16 + n0]);
        float bb[4] = {bv.x, bv.y, bv.z, bv.w};
        float cc[4] = {cv.x, cv.y, cv.z, cv.w};
        float y = 0.f;
#pragma unroll
        for (int j = 0; j < 4; ++j) {
            float ea = __expf(dtv * Aa[j]);
            h[j] = fmaf(ea, h[j], g[j] * (du * bb[j]));
            g[j] *= ea;
            y = fmaf(h[j], cc[j], y);
        }
        y += __shfl_xor(y, 16, 64);
        y += __shfl_xor(y, 32, 64);
        if (ng == 0) {
            float o2 = y + uv * Dm;
            o2 = fminf(fmaxf(o2, -10000.f), 10000.f);
            out[((size_t)(b * S_ + s0 + s)) * M_ + m] = o2;
        }
    }
}

// ============================================================================
// Fallback pipeline (validated R4) — used only if cooperative launch refused.
// ============================================================================
__global__ __launch_bounds__(256) void k_dt(const float* __restrict__ delta,
                                            const float* __restrict__ Wdt,
                                            const float* __restrict__ bdt,
                                            const float* __restrict__ Bw,
                                            const float* __restrict__ Cw,
                                            float* __restrict__ dt,
                                            float* __restrict__ BwT,
                                            float* __restrict__ CwT) {
    int bid = blockIdx.y * 4 + blockIdx.x;
    if (threadIdx.x < 8) {
        int idx = bid * 8 + threadIdx.x;
        int mt = idx >> 4, nt = idx & 15;
        BwT[idx] = Bw[nt * M_ + mt];
        CwT[idx] = Cw[nt * M_ + mt];
    }
    int m    = blockIdx.x * 256 + threadIdx.x;
    int row0 = blockIdx.y * 8;
    float w[R_];
    const float4* W4 = reinterpret_cast<const float4*>(Wdt + (size_t)m * R_);
#pragma unroll
    for (int i = 0; i < R_ / 4; ++i) {
        float4 v = W4[i];
        w[4*i] = v.x; w[4*i+1] = v.y; w[4*i+2] = v.z; w[4*i+3] = v.w;
    }
    float bias = bdt[m];
#pragma unroll 1
    for (int r = 0; r < 8; ++r) {
        int bs = row0 + r;
        const float* dr = delta + (size_t)bs * R_;
        float acc = bias;
#pragma unroll
        for (int k = 0; k < R_; ++k) acc = fmaf(dr[k], w[k], acc);
        float sp = fmaxf(acc, 0.f) + log1pf(expf(-fabsf(acc)));
        sp = fminf(fmaxf(sp, 1e-6f), 10.0f);
        dt[(size_t)bs * M_ + m] = sp;
    }
}

__global__ __launch_bounds__(256) void k_bc_partial(const float* __restrict__ u,
                                                    const float* __restrict__ BwT,
                                                    const float* __restrict__ CwT,
                                                    float* __restrict__ pB,
                                                    float* __restrict__ pC) {
    __shared__ float uLds[16 * 516];
    int r0 = blockIdx.x * 16;
    int k0 = blockIdx.y * 512;
    for (int i = threadIdx.x; i < 2048; i += 256) {
        int r = i >> 7, kq = i & 127;
        float4 v = *reinterpret_cast<const float4*>(&u[(size_t)(r0 + r) * M_ + k0 + kq * 4]);
        *reinterpret_cast<float4*>(&uLds[r * 516 + kq * 4]) = v;
    }
    __syncthreads();
    int r = threadIdx.x >> 4, n = threadIdx.x & 15;
    const float4* u4 = reinterpret_cast<const float4*>(uLds + r * 516);
    float accB = 0.f, accC = 0.f;
#pragma unroll 4
    for (int k4 = 0; k4 < 128; ++k4) {
        float4 uv = u4[k4];
        int kb = k0 + k4 * 4;
        accB = fmaf(uv.x, BwT[(kb+0)*16 + n], accB);
        accB = fmaf(uv.y, BwT[(kb+1)*16 + n], accB);
        accB = fmaf(uv.z, BwT[(kb+2)*16 + n], accB);
        accB = fmaf(uv.w, BwT[(kb+3)*16 + n], accB);
        accC = fmaf(uv.x, CwT[(kb+0)*16 + n], accC);
        accC = fmaf(uv.y, CwT[(kb+1)*16 + n], accC);
        accC = fmaf(uv.z, CwT[(kb+2)*16 + n], accC);
        accC = fmaf(uv.w, CwT[(kb+3)*16 + n], accC);
    }
    size_t o = (size_t)blockIdx.y * 65536 + (size_t)(r0 + r) * 16 + n;
    pB[o] = accB;
    pC[o] = accC;
}

__global__ __launch_bounds__(256) void k_pass1(const float* __restrict__ dt,
                                               const float* __restrict__ u,
                                               const float* __restrict__ pB,
                                               const float* __restrict__ A_log,
                                               float* __restrict__ P,
                                               float* __restrict__ H) {
    __shared__ float ldsDt[CH * 64], ldsU[CH * 64], ldsB[CH * 16];
    int m0 = blockIdx.x * 64, c = blockIdx.y, b = blockIdx.z;
    int s0 = c * CH;
    int tid = threadIdx.x;
    for (int i = tid; i < 512; i += 256) {
        int s = i >> 4, mq = (i & 15) * 4;
        size_t off = ((size_t)(b * S_ + s0 + s)) * M_ + m0 + mq;
        *reinterpret_cast<float4*>(&ldsDt[s * 64 + mq]) = *reinterpret_cast<const float4*>(&dt[off]);
        *reinterpret_cast<float4*>(&ldsU [s * 64 + mq]) = *reinterpret_cast<const float4*>(&u[off]);
    }
    {
        size_t base = (size_t)(b * S_ + s0) * N_;
        for (int i = tid; i < CH * 16; i += 256)
            ldsB[i] = pB[base + i] + pB[65536 + base + i];
    }
    __syncthreads();
    int lane = tid & 63, wave = tid >> 6;
    int ml = wave * 16 + (lane & 15);
    int m  = m0 + ml;
    int n0 = (lane >> 4) * 4;
    float Aa[4], h[4] = {0,0,0,0}, g[4] = {1.f,1.f,1.f,1.f};
#pragma unroll
    for (int j = 0; j < 4; ++j) {
        float a = -expf(A_log[(size_t)(n0 + j) * M_ + m]);
        Aa[j] = fminf(fmaxf(a, -10.f), -1e-6f);
    }
    for (int s = 0; s < CH; ++s) {
        float dtv = ldsDt[s * 64 + ml];
        float uv  = ldsU [s * 64 + ml];
        float du  = dtv * uv;
        float4 bv = *reinterpret_cast<const float4*>(&ldsB[s * 16 + n0]);
        float bb[4] = {bv.x, bv.y, bv.z, bv.w};
#pragma unroll
        for (int j = 0; j < 4; ++j) {
            float ea = __expf(dtv * Aa[j]);
            h[j] = fmaf(ea, h[j], g[j] * (du * bb[j]));
            g[j] *= ea;
        }
    }
#pragma unroll
    for (int j = 0; j < 4; ++j) {
        size_t o = ((size_t)(b * 16 + n0 + j) * NC + c) * M_ + m;
        P[o] = g[j];
        H[o] = h[j];
    }
}

__global__ __launch_bounds__(64) void k_pass2(float* __restrict__ P,
                                              float* __restrict__ H) {
    int idx = blockIdx.x * 64 + threadIdx.x;
    int m = idx & (M_ - 1);
    int n = (idx >> 10) & 15;
    int b = idx >> 14;
    size_t base = ((size_t)(b * 16 + n) * NC) * M_ + m;
    float grun = 1.f, hrun = 0.f;
#pragma unroll 1
    for (int c0 = 0; c0 < NC; c0 += 8) {
        float pv[8], hv[8];
#pragma unroll
        for (int t = 0; t < 8; ++t) {
            pv[t] = P[base + (size_t)(c0 + t) * M_];
            hv[t] = H[base + (size_t)(c0 + t) * M_];
        }
#pragma unroll
        for (int t = 0; t < 8; ++t) {
            P[base + (size_t)(c0 + t) * M_] = grun;
            H[base + (size_t)(c0 + t) * M_] = hrun;
            hrun = fmaf(pv[t], hrun, grun * hv[t]);
            grun *= pv[t];
        }
    }
}

__global__ __launch_bounds__(256) void k_pass3(const float* __restrict__ dt,
                                               const float* __restrict__ u,
                                               const float* __restrict__ pB,
                                               const float* __restrict__ pC,
                                               const float* __restrict__ A_log,
                                               const float* __restrict__ Dskip,
                                               const float* __restrict__ Pinit,
                                               const float* __restrict__ Hinit,
                                               float* __restrict__ out) {
    __shared__ float ldsDt[CH * 64], ldsU[CH * 64], ldsB[CH * 16], ldsC[CH * 16];
    int m0 = blockIdx.x * 64, c = blockIdx.y, b = blockIdx.z;
    int s0 = c * CH;
    int tid = threadIdx.x;
    for (int i = tid; i < 512; i += 256) {
        int s = i >> 4, mq = (i & 15) * 4;
        size_t off = ((size_t)(b * S_ + s0 + s)) * M_ + m0 + mq;
        *reinterpret_cast<float4*>(&ldsDt[s * 64 + mq]) = *reinterpret_cast<const float4*>(&dt[off]);
        *reinterpret_cast<float4*>(&ldsU [s * 64 + mq]) = *reinterpret_cast<const float4*>(&u[off]);
    }
    {
        size_t base = (size_t)(b * S_ + s0) * N_;
        for (int i = tid; i < CH * 16; i += 256) {
            ldsB[i] = pB[base + i] + pB[65536 + base + i];
            ldsC[i] = pC[base + i] + pC[65536 + base + i];
        }
    }
    __syncthreads();
    int lane = tid & 63, wave = tid >> 6;
    int ml = wave * 16 + (lane & 15);
    int m  = m0 + ml;
    int ng = lane >> 4, n0 = ng * 4;
    float Aa[4], h[4], g[4];
#pragma unroll
    for (int j = 0; j < 4; ++j) {
        float a = -expf(A_log[(size_t)(n0 + j) * M_ + m]);
        Aa[j] = fminf(fmaxf(a, -10.f), -1e-6f);
        size_t o = ((size_t)(b * 16 + n0 + j) * NC + c) * M_ + m;
        g[j] = Pinit[o];
        h[j] = Hinit[o];
    }
    float Dm = Dskip[m];
    for (int s = 0; s < CH; ++s) {
        float dtv = ldsDt[s * 64 + ml];
        float uv  = ldsU [s * 64 + ml];
        float du  = dtv * uv;
        float4 bv = *reinterpret_cast<const float4*>(&ldsB[s * 16 + n0]);
        float4 cv = *reinterpret_cast<const float4*>(&ldsC[s * 16 + n0]);
        float bb[4] = {bv.x, bv.y, bv.z, bv.w};
        float cc[4] = {cv.x, cv.y, cv.z, cv.w};
        float y = 0.f;
#pragma unroll
        for (int j = 0; j < 4; ++j) {
            float ea = __expf(dtv * Aa[j]);
            h[j] = fmaf(ea, h[j], g[j] * (du * bb[j]));
            g[j] *= ea;
            y = fmaf(h[j], cc[j], y);
        }
        y += __shfl_xor(y, 16, 64);
        y += __shfl_xor(y, 32, 64);
        if (ng == 0) {
            float o = y + uv * Dm;
            o = fminf(fmaxf(o, -10000.f), 10000.f);
            out[((size_t)(b * S_ + s0 + s)) * M_ + m] = o;
        }
    }
}

extern "C" void kernel_launch(void* const* d_in, const int* in_sizes, int n_in,
                              void* d_out, int out_size, void* d_ws, size_t ws_size,
                              hipStream_t stream) {
    const float* u     = (const float*)d_in[0];
    const float* delta = (const float*)d_in[1];
    const float* Wdt   = (const float*)d_in[2];
    const float* bdt   = (const float*)d_in[3];
    const float* A_log = (const float*)d_in[4];
    const float* Dski  = (const float*)d_in[5];
    const float* Bw    = (const float*)d_in[6];
    const float* Cw    = (const float*)d_in[7];
    float* out = (float*)d_out;
    float* ws  = (float*)d_ws;

    float* dt  = ws + DT_OFF;
    float* P   = ws + P_OFF;
    float* H   = ws + H_OFF;
    float* BwT = ws + BWT_OFF;
    float* CwT = ws + CWT_OFF;
    float* pB  = ws + PB_OFF;
    float* pC  = ws + PC_OFF;

    // Cooperative path: requires full co-residency (8 blocks/CU x 256 CUs).
    int maxBlk = 0;
    hipError_t qerr = hipOccupancyMaxActiveBlocksPerMultiprocessor(
        &maxBlk, reinterpret_cast<const void*>(k_mega), 256, 0);
    if (qerr == hipSuccess && maxBlk >= 8) {
        void* args[] = {(void*)&u, (void*)&delta, (void*)&Wdt, (void*)&bdt,
                        (void*)&A_log, (void*)&Dski, (void*)&Bw, (void*)&Cw,
                        (void*)&P, (void*)&H, (void*)&pB, (void*)&pC, (void*)&out};
        hipError_t lerr = hipLaunchCooperativeKernel(
            reinterpret_cast<const void*>(k_mega), dim3(2048), dim3(256),
            args, 0, stream);
        if (lerr == hipSuccess) return;
    }

    // Fallback: validated 5-kernel pipeline.
    k_dt<<<dim3(4, 512), 256, 0, stream>>>(delta, Wdt, bdt, Bw, Cw, dt, BwT, CwT);
    k_bc_partial<<<dim3(256, 2), 256, 0, stream>>>(u, BwT, CwT, pB, pC);
    k_pass1<<<dim3(16, NC, B_), 256, 0, stream>>>(dt, u, pB, A_log, P, H);
    k_pass2<<<512, 64, 0, stream>>>(P, H);
    k_pass3<<<dim3(16, NC, B_), 256, 0, stream>>>(dt, u, pB, pC, A_log, Dski, P, H, out);
}